// Round 5
// baseline (335.510 us; speedup 1.0000x reference)
//
#include <hip/hip_runtime.h>
#include <hip/hip_cooperative_groups.h>

namespace cg = cooperative_groups;

#define C_SEG 4096
#define E_CH 16
#define NE_EDGES 16384
#define P_PIX (1024 * 1024)
#define NCHUNK 32
#define CHUNK_PIX (P_PIX / NCHUNK)   // 32768
#define NBLK 512
#define SCALE 262144.0f              // 2^18 fixed point
#define INV_SCALE (1.0f / 262144.0f)
#define BIAS_PER_ADD (1ll << 22)     // per-add bias keeps value field positive
#define CNT_ONE (1ull << 44)         // count field at bits 44..63
#define VAL_MASK ((1ull << 44) - 1)

// ws layout (byte offsets):
//   0x000000  sums_part[16][32][4096] f32    8 MB
//   0x800000  cnt_part[32][4096]      f32  512 KB
//   0x880000  msum[4096][16]          f32  256 KB   (UNnormalized sums)
//   0x8C0000  inv_n[4096]             f32   16 KB
//   0x8C4000  part[512]               f32    2 KB

// ---------------------------------------------------------------------------
// Phase A: one (chunk, channel) tile per virtual block. Packed u64 LDS
// atomics: one ds_add_u64 accumulates count (hi 20 bits) + biased fixed-point
// value (lo 44 bits). Fire-and-forget (no return) -> throughput-bound.
// ---------------------------------------------------------------------------
__device__ __forceinline__ void phaseA(int vb, int t,
                                       const float* __restrict__ emb,
                                       const int* __restrict__ seg,
                                       float* __restrict__ sums_part,
                                       float* __restrict__ cnt_part,
                                       unsigned long long* bins) {
    const int chunk = vb & (NCHUNK - 1);
    const int ch = vb >> 5;
    for (int i = t; i < C_SEG; i += 256) bins[i] = 0ull;
    __syncthreads();

    const int base = chunk * CHUNK_PIX;
    const float* ec = emb + (size_t)ch * P_PIX;
    for (int it = 0; it < 32; ++it) {
        const int idx = base + (it * 256 + t) * 4;
        const int4 s4 = *(const int4*)(seg + idx);
        const float4 v = *(const float4*)(ec + idx);
        atomicAdd(&bins[s4.x],
                  CNT_ONE + (unsigned long long)(llrintf(v.x * SCALE) + BIAS_PER_ADD));
        atomicAdd(&bins[s4.y],
                  CNT_ONE + (unsigned long long)(llrintf(v.y * SCALE) + BIAS_PER_ADD));
        atomicAdd(&bins[s4.z],
                  CNT_ONE + (unsigned long long)(llrintf(v.z * SCALE) + BIAS_PER_ADD));
        atomicAdd(&bins[s4.w],
                  CNT_ONE + (unsigned long long)(llrintf(v.w * SCALE) + BIAS_PER_ADD));
    }
    __syncthreads();

    float* dst = sums_part + ((size_t)ch * NCHUNK + chunk) * C_SEG;
    for (int i = t; i < C_SEG; i += 256) {
        const unsigned long long p = bins[i];
        const long long cnt = (long long)(p >> 44);
        const long long val = (long long)(p & VAL_MASK) - cnt * BIAS_PER_ADD;
        dst[i] = (float)val * INV_SCALE;
        if (ch == 0) cnt_part[(size_t)chunk * C_SEG + i] = (float)cnt;
    }
}

// ---------------------------------------------------------------------------
// Phase B: merge chunk partials. vb<256: sums (coalesced over segs);
// vb in [256,272): counts -> inv_n.
// ---------------------------------------------------------------------------
__device__ __forceinline__ void phaseB(int vb, int t,
                                       const float* __restrict__ sums_part,
                                       const float* __restrict__ cnt_part,
                                       float* __restrict__ msum,
                                       float* __restrict__ inv_n) {
    if (vb < 256) {
        const int c = vb >> 4;
        const int s = (vb & 15) * 256 + t;
        const float* src = sums_part + (size_t)c * NCHUNK * C_SEG + s;
        float acc = 0.0f;
#pragma unroll
        for (int k = 0; k < NCHUNK; ++k) acc += src[(size_t)k * C_SEG];
        msum[s * E_CH + c] = acc;
    } else if (vb < 272) {
        const int s = (vb - 256) * 256 + t;
        float acc = 0.0f;
#pragma unroll
        for (int k = 0; k < NCHUNK; ++k) acc += cnt_part[(size_t)k * C_SEG + s];
        inv_n[s] = 1.0f / fmaxf(acc, 1.0f);
    }
}

// ---------------------------------------------------------------------------
// Phase C helpers: per-quad intra term and per-edge inter term.
// ---------------------------------------------------------------------------
__device__ __forceinline__ float quad_term(int q, const float* __restrict__ emb,
                                           const int* __restrict__ seg,
                                           const float* __restrict__ msum,
                                           const float* __restrict__ inv_n) {
    const int4 s4 = *(const int4*)(seg + q * 4);
    const float inx = inv_n[s4.x], iny = inv_n[s4.y];
    const float inz = inv_n[s4.z], inw = inv_n[s4.w];
    const float4* emb4 = (const float4*)emb;
    const float4* rA = (const float4*)(msum + s4.x * E_CH);
    const float4* rB = (const float4*)(msum + s4.y * E_CH);
    const float4* rC = (const float4*)(msum + s4.z * E_CH);
    const float4* rD = (const float4*)(msum + s4.w * E_CH);

    float dx = 0.f, dy = 0.f, dz = 0.f, dw = 0.f;
#pragma unroll
    for (int j = 0; j < 4; ++j) {
        const float4 a = rA[j], b4 = rB[j], c4 = rC[j], d4 = rD[j];
        const float* aF = (const float*)&a;
        const float* bF = (const float*)&b4;
        const float* cF = (const float*)&c4;
        const float* dF = (const float*)&d4;
#pragma unroll
        for (int cc = 0; cc < 4; ++cc) {
            const float4 e = emb4[(size_t)(j * 4 + cc) * (P_PIX / 4) + q];
            dx = fmaf(e.x, aF[cc], dx);
            dy = fmaf(e.y, bF[cc], dy);
            dz = fmaf(e.z, cF[cc], dz);
            dw = fmaf(e.w, dF[cc], dw);
        }
    }
    return fmaxf(0.5f - inx * dx, 0.0f) * inx +
           fmaxf(0.5f - iny * dy, 0.0f) * iny +
           fmaxf(0.5f - inz * dz, 0.0f) * inz +
           fmaxf(0.5f - inw * dw, 0.0f) * inw;
}

__device__ __forceinline__ float edge_term(int e, const int* __restrict__ edges,
                                           const float* __restrict__ w,
                                           const float* __restrict__ msum,
                                           const float* __restrict__ inv_n) {
    const int u = edges[e];
    const int vv = edges[NE_EDGES + e];
    const float4* mu = (const float4*)(msum + u * E_CH);
    const float4* mv = (const float4*)(msum + vv * E_CH);
    float dot = 0.0f;
#pragma unroll
    for (int j = 0; j < 4; ++j) {
        const float4 a = mu[j];
        const float4 b = mv[j];
        dot = fmaf(a.x, b.x, dot);
        dot = fmaf(a.y, b.y, dot);
        dot = fmaf(a.z, b.z, dot);
        dot = fmaf(a.w, b.w, dot);
    }
    const float d = 1.0f - inv_n[u] * inv_n[vv] * dot;
    return fmaxf(1.5f - d * w[e], 0.0f);
}

__device__ __forceinline__ void phaseC(int vb, int t,
                                       const float* __restrict__ emb,
                                       const int* __restrict__ seg,
                                       const int* __restrict__ edges,
                                       const float* __restrict__ w,
                                       const float* __restrict__ msum,
                                       const float* __restrict__ inv_n,
                                       float* __restrict__ part,
                                       float* red) {
    const int q0 = vb * 512 + t;
    float v = quad_term(q0, emb, seg, msum, inv_n) +
              quad_term(q0 + 256, emb, seg, msum, inv_n);
    v *= (1.0f / (float)C_SEG);
    if (t < 32) {
        v += edge_term(vb * 32 + t, edges, w, msum, inv_n) *
             (1.0f / (float)NE_EDGES);
    }
    for (int o = 32; o > 0; o >>= 1) v += __shfl_down(v, o, 64);
    __syncthreads();
    if ((t & 63) == 0) red[t >> 6] = v;
    __syncthreads();
    if (t == 0) part[vb] = red[0] + red[1] + red[2] + red[3];
}

// ---------------------------------------------------------------------------
// Fused cooperative kernel: 512 blocks x 256 (2 blocks/CU, 2x margin under
// the 4/CU resource cap so the cooperative launch cannot be rejected).
// ---------------------------------------------------------------------------
__global__ __launch_bounds__(256, 4) void k_fused(
    const float* __restrict__ emb, const int* __restrict__ seg,
    const int* __restrict__ edges, const float* __restrict__ w,
    float* __restrict__ sums_part, float* __restrict__ cnt_part,
    float* __restrict__ msum, float* __restrict__ inv_n,
    float* __restrict__ part, float* __restrict__ out) {
    __shared__ unsigned long long bins[C_SEG];  // 32 KB, reused per phase
    cg::grid_group grid = cg::this_grid();
    const int b = blockIdx.x;
    const int t = threadIdx.x;

    for (int vb = b; vb < NBLK; vb += gridDim.x)
        phaseA(vb, t, emb, seg, sums_part, cnt_part, bins);
    grid.sync();
    for (int vb = b; vb < 272; vb += gridDim.x)
        phaseB(vb, t, sums_part, cnt_part, msum, inv_n);
    grid.sync();
    for (int vb = b; vb < NBLK; vb += gridDim.x)
        phaseC(vb, t, emb, seg, edges, w, msum, inv_n, part, (float*)bins);
    grid.sync();
    if (b == 0) {
        float v = 0.0f;
        for (int i = t; i < NBLK; i += 256) v += part[i];
        for (int o = 32; o > 0; o >>= 1) v += __shfl_down(v, o, 64);
        float* red = (float*)bins;
        __syncthreads();
        if ((t & 63) == 0) red[t >> 6] = v;
        __syncthreads();
        if (t == 0) out[0] = red[0] + red[1] + red[2] + red[3];
    }
}

// ------------------------- fallback (plain) kernels -------------------------
__global__ __launch_bounds__(256) void kA(const float* __restrict__ emb,
                                          const int* __restrict__ seg,
                                          float* __restrict__ sums_part,
                                          float* __restrict__ cnt_part) {
    __shared__ unsigned long long bins[C_SEG];
    phaseA(blockIdx.x, threadIdx.x, emb, seg, sums_part, cnt_part, bins);
}

__global__ __launch_bounds__(256) void kB(const float* __restrict__ sums_part,
                                          const float* __restrict__ cnt_part,
                                          float* __restrict__ msum,
                                          float* __restrict__ inv_n) {
    phaseB(blockIdx.x, threadIdx.x, sums_part, cnt_part, msum, inv_n);
}

__global__ __launch_bounds__(256) void kC(const float* __restrict__ emb,
                                          const int* __restrict__ seg,
                                          const int* __restrict__ edges,
                                          const float* __restrict__ w,
                                          const float* __restrict__ msum,
                                          const float* __restrict__ inv_n,
                                          float* __restrict__ part) {
    __shared__ float red[4];
    phaseC(blockIdx.x, threadIdx.x, emb, seg, edges, w, msum, inv_n, part, red);
}

__global__ __launch_bounds__(256) void kF(const float* __restrict__ part,
                                          float* __restrict__ out) {
    float v = 0.0f;
    for (int i = threadIdx.x; i < NBLK; i += 256) v += part[i];
    for (int o = 32; o > 0; o >>= 1) v += __shfl_down(v, o, 64);
    __shared__ float red[4];
    const int t = threadIdx.x;
    if ((t & 63) == 0) red[t >> 6] = v;
    __syncthreads();
    if (t == 0) out[0] = red[0] + red[1] + red[2] + red[3];
}

extern "C" void kernel_launch(void* const* d_in, const int* in_sizes, int n_in,
                              void* d_out, int out_size, void* d_ws,
                              size_t ws_size, hipStream_t stream) {
    const float* emb = (const float*)d_in[0];      // (1,16,1024,1024) fp32
    const float* weights = (const float*)d_in[1];  // (16384,) fp32
    const int* seg = (const int*)d_in[2];          // (1,1,1024,1024) int32
    const int* edges = (const int*)d_in[3];        // (2,16384) int32
    float* out = (float*)d_out;

    char* ws = (char*)d_ws;
    float* sums_part = (float*)(ws);
    float* cnt_part = (float*)(ws + 0x800000);
    float* msum = (float*)(ws + 0x880000);
    float* invn = (float*)(ws + 0x8C0000);
    float* part = (float*)(ws + 0x8C4000);

    void* args[] = {(void*)&emb,       (void*)&seg,      (void*)&edges,
                    (void*)&weights,   (void*)&sums_part, (void*)&cnt_part,
                    (void*)&msum,      (void*)&invn,      (void*)&part,
                    (void*)&out};
    const hipError_t err = hipLaunchCooperativeKernel(
        (void*)k_fused, dim3(NBLK), dim3(256), args, 0, stream);
    if (err != hipSuccess) {
        // Cooperative launch unavailable (or rejected): identical phases as
        // plain kernels. Same ws layout, same math.
        kA<<<NBLK, 256, 0, stream>>>(emb, seg, sums_part, cnt_part);
        kB<<<272, 256, 0, stream>>>(sums_part, cnt_part, msum, invn);
        kC<<<NBLK, 256, 0, stream>>>(emb, seg, edges, weights, msum, invn,
                                     part);
        kF<<<1, 256, 0, stream>>>(part, out);
    }
}

// Round 6
// 149.387 us; speedup vs baseline: 2.2459x; 2.2459x over previous
//
#include <hip/hip_runtime.h>

#define C_SEG 4096
#define E_CH 16
#define NE_EDGES 16384
#define P_PIX (1024 * 1024)
#define NCHUNK 64
#define CHUNK_PIX (P_PIX / NCHUNK)   // 16384
#define SCALE 262144.0f              // 2^18 fixed point
#define INV_SCALE (1.0f / 262144.0f)

// ws layout (byte offsets):
//   0x0000000 sums_part[16][64][4096] f32   16 MB
//   0x1000000 cnt_part[64][4096]      f32    1 MB
//   0x1100000 msum[4096][16]          f32  256 KB   (UNnormalized sums)
//   0x1140000 inv_n[4096]             f32   16 KB
//   0x1144000 part[1024]              f32    4 KB

// ---------------------------------------------------------------------------
// kA: segment sums + counts. 1088 blocks x 512 thr, 16 KB int bins,
// __launch_bounds__(512,8) -> 4 blocks/CU = 32 waves/CU (R3 had ~17; R5's
// coop kernel had 8 and was latency-crippled). Explicit 1-deep prefetch for
// extra MLP. Fire-and-forget ds_add_u32 (int atomics are native).
// vb < 1024: (chunk = vb&63, channel = vb>>6). vb >= 1024: counts for chunk.
// ---------------------------------------------------------------------------
__global__ __launch_bounds__(512, 8) void kA(const float* __restrict__ emb,
                                             const int* __restrict__ seg,
                                             float* __restrict__ sums_part,
                                             float* __restrict__ cnt_part) {
    __shared__ int bins[C_SEG];  // 16 KB
    const int vb = blockIdx.x;
    const int t = threadIdx.x;
    const bool is_cnt = (vb >= 1024);
    const int chunk = is_cnt ? (vb - 1024) : (vb & 63);
    const int base = chunk * CHUNK_PIX;

    for (int i = t; i < C_SEG; i += 512) bins[i] = 0;
    __syncthreads();

    if (!is_cnt) {
        const int ch = vb >> 6;
        const float* ec = emb + (size_t)ch * P_PIX;
        int idx = base + t * 4;
        int4 s4 = *(const int4*)(seg + idx);
        float4 v = *(const float4*)(ec + idx);
#pragma unroll
        for (int it = 0; it < 8; ++it) {
            const int4 s4c = s4;
            const float4 vc = v;
            if (it < 7) {  // prefetch next iteration before the atomics
                idx += 512 * 4;
                s4 = *(const int4*)(seg + idx);
                v = *(const float4*)(ec + idx);
            }
            atomicAdd(&bins[s4c.x], __float2int_rn(vc.x * SCALE));
            atomicAdd(&bins[s4c.y], __float2int_rn(vc.y * SCALE));
            atomicAdd(&bins[s4c.z], __float2int_rn(vc.z * SCALE));
            atomicAdd(&bins[s4c.w], __float2int_rn(vc.w * SCALE));
        }
        __syncthreads();
        float* dst = sums_part + ((size_t)ch * NCHUNK + chunk) * C_SEG;
        for (int i = t; i < C_SEG; i += 512)
            dst[i] = (float)bins[i] * INV_SCALE;
    } else {
#pragma unroll
        for (int it = 0; it < 8; ++it) {
            const int idx = base + (it * 512 + t) * 4;
            const int4 s4 = *(const int4*)(seg + idx);
            atomicAdd(&bins[s4.x], 1);
            atomicAdd(&bins[s4.y], 1);
            atomicAdd(&bins[s4.z], 1);
            atomicAdd(&bins[s4.w], 1);
        }
        __syncthreads();
        float* cd = cnt_part + (size_t)chunk * C_SEG;
        for (int i = t; i < C_SEG; i += 512) cd[i] = (float)bins[i];
    }
}

// ---------------------------------------------------------------------------
// kB: merge chunk partials. 272 blocks x 256. vb<256: sums (16 blocks per
// channel, coalesced over segs); vb in [256,272): counts -> inv_n.
// ---------------------------------------------------------------------------
__global__ __launch_bounds__(256) void kB(const float* __restrict__ sums_part,
                                          const float* __restrict__ cnt_part,
                                          float* __restrict__ msum,
                                          float* __restrict__ inv_n) {
    const int vb = blockIdx.x, t = threadIdx.x;
    if (vb < 256) {
        const int c = vb >> 4;
        const int s = (vb & 15) * 256 + t;
        const float* src = sums_part + (size_t)c * NCHUNK * C_SEG + s;
        float acc = 0.0f;
#pragma unroll
        for (int k = 0; k < NCHUNK; ++k) acc += src[(size_t)k * C_SEG];
        msum[s * E_CH + c] = acc;  // UNnormalized
    } else {
        const int s = (vb - 256) * 256 + t;
        float acc = 0.0f;
#pragma unroll
        for (int k = 0; k < NCHUNK; ++k) acc += cnt_part[(size_t)k * C_SEG + s];
        inv_n[s] = 1.0f / fmaxf(acc, 1.0f);
    }
}

// ---------------------------------------------------------------------------
// kC: intra (4 px/thread, float4) + 16 edges/block. 1024 blocks x 256.
// One partial per block, no same-address atomics.
// ---------------------------------------------------------------------------
__global__ __launch_bounds__(256, 4) void kC(const float* __restrict__ emb,
                                             const int* __restrict__ seg,
                                             const int* __restrict__ edges,
                                             const float* __restrict__ w,
                                             const float* __restrict__ msum,
                                             const float* __restrict__ inv_n,
                                             float* __restrict__ part) {
    const int b = blockIdx.x, t = threadIdx.x;
    const int q = b * 256 + t;  // quad index, 262144 total
    const int4 s4 = *(const int4*)(seg + q * 4);
    const float inx = inv_n[s4.x], iny = inv_n[s4.y];
    const float inz = inv_n[s4.z], inw = inv_n[s4.w];
    const float4* emb4 = (const float4*)emb;
    const float4* rA = (const float4*)(msum + s4.x * E_CH);
    const float4* rB = (const float4*)(msum + s4.y * E_CH);
    const float4* rC = (const float4*)(msum + s4.z * E_CH);
    const float4* rD = (const float4*)(msum + s4.w * E_CH);

    float dx = 0.f, dy = 0.f, dz = 0.f, dw = 0.f;
#pragma unroll
    for (int j = 0; j < 4; ++j) {
        const float4 a = rA[j], b4 = rB[j], c4 = rC[j], d4 = rD[j];
        const float* aF = (const float*)&a;
        const float* bF = (const float*)&b4;
        const float* cF = (const float*)&c4;
        const float* dF = (const float*)&d4;
#pragma unroll
        for (int cc = 0; cc < 4; ++cc) {
            const float4 e = emb4[(size_t)(j * 4 + cc) * (P_PIX / 4) + q];
            dx = fmaf(e.x, aF[cc], dx);
            dy = fmaf(e.y, bF[cc], dy);
            dz = fmaf(e.z, cF[cc], dz);
            dw = fmaf(e.w, dF[cc], dw);
        }
    }
    // dot_p = inv_n * sdot; term = max(0.5 - dot_p, 0) * inv_n
    float v = (fmaxf(0.5f - inx * dx, 0.0f) * inx +
               fmaxf(0.5f - iny * dy, 0.0f) * iny +
               fmaxf(0.5f - inz * dz, 0.0f) * inz +
               fmaxf(0.5f - inw * dw, 0.0f) * inw) *
              (1.0f / (float)C_SEG);

    if (t < 16) {  // 16 edges per block
        const int e = b * 16 + t;
        const int u = edges[e];
        const int vv = edges[NE_EDGES + e];
        const float4* mu = (const float4*)(msum + u * E_CH);
        const float4* mv = (const float4*)(msum + vv * E_CH);
        float dot = 0.0f;
#pragma unroll
        for (int j = 0; j < 4; ++j) {
            const float4 a = mu[j];
            const float4 bb = mv[j];
            dot = fmaf(a.x, bb.x, dot);
            dot = fmaf(a.y, bb.y, dot);
            dot = fmaf(a.z, bb.z, dot);
            dot = fmaf(a.w, bb.w, dot);
        }
        const float d = 1.0f - inv_n[u] * inv_n[vv] * dot;
        v += fmaxf(1.5f - d * w[e], 0.0f) * (1.0f / (float)NE_EDGES);
    }

    for (int o = 32; o > 0; o >>= 1) v += __shfl_down(v, o, 64);
    __shared__ float red[4];
    if ((t & 63) == 0) red[t >> 6] = v;
    __syncthreads();
    if (t == 0) part[b] = red[0] + red[1] + red[2] + red[3];
}

// ---------------------------------------------------------------------------
// kF: sum 1024 partials -> scalar.
// ---------------------------------------------------------------------------
__global__ __launch_bounds__(256) void kF(const float* __restrict__ part,
                                          float* __restrict__ out) {
    float v = 0.0f;
    for (int i = threadIdx.x; i < 1024; i += 256) v += part[i];
    for (int o = 32; o > 0; o >>= 1) v += __shfl_down(v, o, 64);
    __shared__ float red[4];
    const int t = threadIdx.x;
    if ((t & 63) == 0) red[t >> 6] = v;
    __syncthreads();
    if (t == 0) out[0] = red[0] + red[1] + red[2] + red[3];
}

extern "C" void kernel_launch(void* const* d_in, const int* in_sizes, int n_in,
                              void* d_out, int out_size, void* d_ws,
                              size_t ws_size, hipStream_t stream) {
    const float* emb = (const float*)d_in[0];      // (1,16,1024,1024) fp32
    const float* weights = (const float*)d_in[1];  // (16384,) fp32
    const int* seg = (const int*)d_in[2];          // (1,1,1024,1024) int32
    const int* edges = (const int*)d_in[3];        // (2,16384) int32
    float* out = (float*)d_out;

    char* ws = (char*)d_ws;
    float* sums_part = (float*)(ws);
    float* cnt_part = (float*)(ws + 0x1000000);
    float* msum = (float*)(ws + 0x1100000);
    float* invn = (float*)(ws + 0x1140000);
    float* part = (float*)(ws + 0x1144000);

    kA<<<1088, 512, 0, stream>>>(emb, seg, sums_part, cnt_part);
    kB<<<272, 256, 0, stream>>>(sums_part, cnt_part, msum, invn);
    kC<<<1024, 256, 0, stream>>>(emb, seg, edges, weights, msum, invn, part);
    kF<<<1, 256, 0, stream>>>(part, out);
}